// Round 7
// baseline (2049.355 us; speedup 1.0000x reference)
//
#include <hip/hip_runtime.h>
#include <hip/hip_bf16.h>

#define B_   64
#define T_   512
#define E_   300
#define U_   512
#define G4_  2048
#define D1_  1024
#define D2_  1024
#define NC_  20
#define KP_  320          // E_ padded to multiple of 32 for MFMA

// LSTM decomposition: 16 batch-groups (4 batches) x 16 unit-slices (32 units)
#define NBG_ 16
// dynamic LDS layout for lstm_kernel
#define WH_OFF   0
#define WH_BYTES (128 * 520 * 2)          // 133120: whsT[128][520] bf16
#define HS_OFF   (WH_OFF + WH_BYTES)
#define HS_BYTES (2 * 4 * 520 * 2)        // 8320: hs[parity][4 batches][520] bf16
#define MK_OFF   (HS_OFF + HS_BYTES)
#define MK_BYTES (4 * 16 * 4)             // 256:  masks[4][16]
#define DN_OFF   (MK_OFF + MK_BYTES)
#define DN_BYTES (16 * 4)                 // 64:   done[16] cumulative counters
#define SMEM_TOTAL (DN_OFF + DN_BYTES)    // 141760 <= 160 KiB

typedef __bf16 bf16x8 __attribute__((ext_vector_type(8)));
typedef float  f32x4  __attribute__((ext_vector_type(4)));

__device__ __forceinline__ float sigmoidf_(float x) { return 1.0f / (1.0f + __expf(-x)); }

__device__ __forceinline__ void gl_lds16(const void* g, void* l) {
    __builtin_amdgcn_global_load_lds(
        (const __attribute__((address_space(1))) unsigned int*)g,
        (__attribute__((address_space(3))) unsigned int*)l, 16, 0, 0);
}

__device__ __forceinline__ unsigned long long coh_load8(const unsigned long long* p) {
    uint2 v;
    asm volatile("global_load_dwordx2 %0, %1, off sc0 sc1\n\t"
                 "s_waitcnt vmcnt(0)"
                 : "=&v"(v) : "v"(p) : "memory");
    unsigned long long r;
    __builtin_memcpy(&r, &v, 8);
    return r;
}

__device__ __forceinline__ unsigned tag4_(unsigned long long v) {
    return (unsigned)(((v >> 15) & 1ull) | ((v >> 30) & 2ull) |
                      ((v >> 45) & 4ull) | ((v >> 60) & 8ull));
}

// ---------------------------------------------------------------------------
// prep: Wx (300x2048 f32) -> WxT[2048][320] bf16 (transposed, K zero-padded)
// ---------------------------------------------------------------------------
__global__ __launch_bounds__(256) void prep_wxT(const float* __restrict__ Wx,
                                                __hip_bfloat16* __restrict__ wxT) {
    __shared__ __hip_bfloat16 t[64][65];
    const int n0 = blockIdx.x * 64;   // 32 tiles
    const int k0 = blockIdx.y * 64;   // 5 tiles
    const int tid = threadIdx.x;
    for (int i = tid; i < 4096; i += 256) {
        int r = i >> 6, c = i & 63;
        int k = k0 + r;
        float v = (k < E_) ? Wx[(size_t)k * G4_ + n0 + c] : 0.f;
        t[r][c] = __float2bfloat16(v);
    }
    __syncthreads();
    for (int i = tid; i < 4096; i += 256) {
        int r = i >> 6, c = i & 63;
        wxT[(size_t)(n0 + r) * KP_ + k0 + c] = t[c][r];
    }
}

// ---------------------------------------------------------------------------
// prep: gather + cvt  xb[bt][k] = bf16(emb[tokens[bt]][k]), zero-padded K
// ---------------------------------------------------------------------------
__global__ __launch_bounds__(256) void prep_xb(const int* __restrict__ tokens,
                                               const float* __restrict__ emb,
                                               __hip_bfloat16* __restrict__ xb) {
    const int row = blockIdx.x * 4 + (threadIdx.x >> 6);
    const int ln  = threadIdx.x & 63;
    const int tok = tokens[row];
    const float* src = emb + (size_t)tok * E_;
    __hip_bfloat16* dst = xb + (size_t)row * KP_;
    for (int k = ln; k < KP_; k += 64)
        dst[k] = (k < E_) ? __float2bfloat16(src[k]) : __float2bfloat16(0.f);
}

// ---------------------------------------------------------------------------
// xg GEMM (MFMA): xg[t][b][n] = xb[bt] @ WxT^T + bias   (m97-style 128x128)
// ---------------------------------------------------------------------------
__global__ __launch_bounds__(256) void xg_gemm(const __hip_bfloat16* __restrict__ xb,
                                               const __hip_bfloat16* __restrict__ wxT,
                                               const float* __restrict__ bias,
                                               __hip_bfloat16* __restrict__ xg) {
    const int n0g = blockIdx.x * 128;   // 16
    const int bt0 = blockIdx.y * 128;   // 256
    const int tid = threadIdx.x;
    const int w   = tid >> 6;
    const int ln  = tid & 63;
    const int fn  = ln & 15;
    const int quad = ln >> 4;
    const int m0  = (w >> 1) * 64;
    const int n0w = (w & 1) * 64;

    __shared__ __align__(16) __hip_bfloat16 As[128 * 32];
    __shared__ __align__(16) __hip_bfloat16 Bs[128 * 32];

    f32x4 acc[4][4];
    #pragma unroll
    for (int im = 0; im < 4; ++im)
        #pragma unroll
        for (int in = 0; in < 4; ++in)
            acc[im][in] = (f32x4){0.f, 0.f, 0.f, 0.f};

    const __hip_bfloat16* ga = xb  + (size_t)(bt0 + w * 32 + (ln >> 2)) * KP_ + (ln & 3) * 8;
    const __hip_bfloat16* gb = wxT + (size_t)(n0g + w * 32 + (ln >> 2)) * KP_ + (ln & 3) * 8;

    for (int kt = 0; kt < KP_ / 32; ++kt) {
        gl_lds16(ga,             &As[(w * 32) * 32]);
        gl_lds16(ga + 16 * KP_,  &As[(w * 32 + 16) * 32]);
        gl_lds16(gb,             &Bs[(w * 32) * 32]);
        gl_lds16(gb + 16 * KP_,  &Bs[(w * 32 + 16) * 32]);
        ga += 32; gb += 32;
        __syncthreads();

        bf16x8 af[4], bfr[4];
        #pragma unroll
        for (int im = 0; im < 4; ++im)
            af[im] = *(const bf16x8*)&As[(m0 + im * 16 + fn) * 32 + quad * 8];
        #pragma unroll
        for (int in = 0; in < 4; ++in)
            bfr[in] = *(const bf16x8*)&Bs[(n0w + in * 16 + fn) * 32 + quad * 8];
        #pragma unroll
        for (int im = 0; im < 4; ++im)
            #pragma unroll
            for (int in = 0; in < 4; ++in)
                acc[im][in] = __builtin_amdgcn_mfma_f32_16x16x32_bf16(
                    af[im], bfr[in], acc[im][in], 0, 0, 0);
        __syncthreads();
    }

    #pragma unroll
    for (int in = 0; in < 4; ++in) {
        const int n = n0g + n0w + in * 16 + fn;
        const float bv = bias[n];
        #pragma unroll
        for (int im = 0; im < 4; ++im) {
            #pragma unroll
            for (int r = 0; r < 4; ++r) {
                int m = bt0 + m0 + im * 16 + quad * 4 + r;   // bt = b*T + t
                int bb = m >> 9, tt = m & 511;
                xg[(size_t)(tt * B_ + bb) * G4_ + n] =
                    __float2bfloat16(acc[im][in][r] + bv);
            }
        }
    }
}

// ---------------------------------------------------------------------------
// LSTM: 256 blocks = 16 bgroups (4 batches) x 16 uslices (32 units).
// Barrier-free dataflow step: per-unit 8B chunks {4x bf16 h (>=0), 4-bit tag
// in sign bits} fire-and-forget through coherent stores; stagers signal
// per-slice LDS counters (workgroup release/acquire); compute waves consume
// K-slices as they arrive; gates harvested by intra-wave shuffles (no gbuf,
// no in-loop __syncthreads). Wh fragments live in registers. 1 block/CU.
// ---------------------------------------------------------------------------
__global__ __launch_bounds__(256, 1) void lstm_kernel(const __hip_bfloat16* __restrict__ xg,
                                                      const int* __restrict__ tokens,
                                                      const float* __restrict__ Wh,
                                                      unsigned long long* __restrict__ hch,
                                                      __hip_bfloat16* __restrict__ hfin) {
    extern __shared__ char smem[];
    __hip_bfloat16 (*whsT)[520] = (__hip_bfloat16(*)[520])(smem + WH_OFF);  // [lc][k]
    unsigned short* hsb         = (unsigned short*)(smem + HS_OFF); // [p][b][520]
    unsigned (*masks)[16]       = (unsigned(*)[16])(smem + MK_OFF);
    int* done                   = (int*)(smem + DN_OFF);

    const int tid  = threadIdx.x;
    const int w    = tid >> 6;
    const int lane = tid & 63;
    const int fn   = lane & 15;
    const int quad = lane >> 4;
    const int us   = blockIdx.x & 15;   // unit-slice: units [us*32, us*32+32)
    const int bg   = blockIdx.x >> 4;   // batch-group: batches [bg*4, bg*4+4)

    // stage Wh slice with wave-local gate mapping:
    // lc = ww*32 + half*16 + f ; gate g = half*2 + (f>>3); unit u = ww*8 + (f&7)
    for (int idx = tid; idx < 128 * 512; idx += 256) {
        int lc = idx & 127, k = idx >> 7;
        int ww = lc >> 5, r = lc & 31;
        int half = r >> 4, f = r & 15;
        int g = half * 2 + (f >> 3);
        int u = ww * 8 + (f & 7);
        int gcol = g * 512 + us * 32 + u;
        whsT[lc][k] = __float2bfloat16(Wh[(size_t)k * G4_ + gcol]);
    }
    // token!=0 bitmasks for the 4 batches
    if (tid < 64) {
        int b = tid >> 4, wi = tid & 15;
        const int4* tp = (const int4*)(tokens + (size_t)(bg * 4 + b) * T_ + wi * 32);
        unsigned bits = 0;
        #pragma unroll
        for (int q = 0; q < 8; ++q) {
            int4 v = tp[q];
            bits |= (v.x != 0 ? 1u : 0u) << (q * 4 + 0);
            bits |= (v.y != 0 ? 1u : 0u) << (q * 4 + 1);
            bits |= (v.z != 0 ? 1u : 0u) << (q * 4 + 2);
            bits |= (v.w != 0 ? 1u : 0u) << (q * 4 + 3);
        }
        masks[b][wi] = bits;
    }
    // hs zero (h_0 = 0, both parities) + done init (h_0 staged => 32)
    for (int i = tid; i < 2 * 4 * 520; i += 256) hsb[i] = 0;
    if (tid < 16) done[tid] = 32;
    __syncthreads();

    // weight fragments to registers (constant across all 512 steps)
    const int lc0 = w * 32 + fn;
    bf16x8 wfr0[16], wfr1[16];
    #pragma unroll
    for (int kk = 0; kk < 16; ++kk) {
        wfr0[kk] = *(const bf16x8*)&whsT[lc0][kk * 32 + quad * 8];       // gates 0,1
        wfr1[kk] = *(const bf16x8*)&whsT[lc0 + 16][kk * 32 + quad * 8];  // gates 2,3
    }

    // per-lane state (lanes 0..7 of each wave): unit w*8+lane, batches 0..3
    float cst[4] = {0.f, 0.f, 0.f, 0.f};
    float hst[4] = {0.f, 0.f, 0.f, 0.f};

    // stager mapping: thread t stages units t and t+256
    const int sl0 = tid >> 5;
    const int sl1 = 8 + (tid >> 5);
    unsigned long long* chbase = hch + (size_t)bg * 2 * 512;   // [parity][unit]
    const unsigned long long* cp0 = chbase + tid;              // + parity*512
    const unsigned long long* cp1 = chbase + tid + 256;

    // xg column offsets for quad-0 lanes (gate g, unit w*8+(fn&7))
    const int xc0 = (fn >> 3) * 512 + us * 32 + w * 8 + (fn & 7);          // gates 0/1
    const int xc1 = xc0 + 1024;                                            // gates 2/3

    for (int s = 0; s < T_; ++s) {
        const int p = s & 1;
        unsigned short* hsu = hsb + p * (4 * 520);

        // xg prefetch (normal loads; in flight during the stage polls)
        float xv0[4], xv1[4];
        if (quad == 0) {
            const __hip_bfloat16* xp = xg + (size_t)(s * B_ + bg * 4) * G4_;
            #pragma unroll
            for (int r = 0; r < 4; ++r) {
                xv0[r] = __bfloat162float(xp[(size_t)r * G4_ + xc0]);
                xv1[r] = __bfloat162float(xp[(size_t)r * G4_ + xc1]);
            }
        }

        // stage h_s: poll own 2 chunks (tag nibble = s&15), scatter, signal
        if (s > 0) {
            const unsigned exp4 = (unsigned)s & 0xFu;
            const unsigned long long* a0 = cp0 + p * 512;
            const unsigned long long* a1 = cp1 + p * 512;
            unsigned long long v0, v1;
            {
                uint2 t0, t1;
                asm volatile(
                    "global_load_dwordx2 %0, %2, off sc0 sc1\n\t"
                    "global_load_dwordx2 %1, %3, off sc0 sc1\n\t"
                    "s_waitcnt vmcnt(0)"
                    : "=&v"(t0), "=&v"(t1) : "v"(a0), "v"(a1) : "memory");
                __builtin_memcpy(&v0, &t0, 8);
                __builtin_memcpy(&v1, &t1, 8);
            }
            while (tag4_(v0) != exp4) {
                __builtin_amdgcn_s_sleep(1);
                v0 = coh_load8(a0);
            }
            {
                unsigned long long pl = v0 & 0x7FFF7FFF7FFF7FFFull;
                hsu[0 * 520 + tid] = (unsigned short)(pl);
                hsu[1 * 520 + tid] = (unsigned short)(pl >> 16);
                hsu[2 * 520 + tid] = (unsigned short)(pl >> 32);
                hsu[3 * 520 + tid] = (unsigned short)(pl >> 48);
            }
            __hip_atomic_fetch_add(&done[sl0], 1, __ATOMIC_RELEASE,
                                   __HIP_MEMORY_SCOPE_WORKGROUP);
            while (tag4_(v1) != exp4) {
                __builtin_amdgcn_s_sleep(1);
                v1 = coh_load8(a1);
            }
            {
                unsigned long long pl = v1 & 0x7FFF7FFF7FFF7FFFull;
                hsu[0 * 520 + tid + 256] = (unsigned short)(pl);
                hsu[1 * 520 + tid + 256] = (unsigned short)(pl >> 16);
                hsu[2 * 520 + tid + 256] = (unsigned short)(pl >> 32);
                hsu[3 * 520 + tid + 256] = (unsigned short)(pl >> 48);
            }
            __hip_atomic_fetch_add(&done[sl1], 1, __ATOMIC_RELEASE,
                                   __HIP_MEMORY_SCOPE_WORKGROUP);
        }

        // arrival-driven GEMM over 16 K-slices
        f32x4 acc0 = (f32x4){0.f, 0.f, 0.f, 0.f};
        f32x4 acc1 = (f32x4){0.f, 0.f, 0.f, 0.f};
        if (quad == 0) {
            #pragma unroll
            for (int r = 0; r < 4; ++r) { acc0[r] = xv0[r]; acc1[r] = xv1[r]; }
        }
        const int thr = 32 * (s + 1);
        #pragma unroll
        for (int ks = 0; ks < 16; ++ks) {
            while (__hip_atomic_load(&done[ks], __ATOMIC_ACQUIRE,
                                     __HIP_MEMORY_SCOPE_WORKGROUP) < thr)
                __builtin_amdgcn_s_sleep(1);
            bf16x8 afr = *(const bf16x8*)&hsu[(fn & 3) * 520 + ks * 32 + quad * 8];
            acc0 = __builtin_amdgcn_mfma_f32_16x16x32_bf16(afr, wfr0[ks], acc0, 0, 0, 0);
            acc1 = __builtin_amdgcn_mfma_f32_16x16x32_bf16(afr, wfr1[ks], acc1, 0, 0, 0);
        }

        // harvest gates via intra-wave shuffles; lanes 0..7 update + store
        const int j = lane & 7;
        const unsigned tag = (unsigned)(s + 1) & 0xFu;
        #pragma unroll
        for (int r = 0; r < 4; ++r) {
            float gi = __shfl(acc0[r], j, 64);        // gate 0 (i),  unit w*8+j
            float gf = __shfl(acc0[r], j + 8, 64);    // gate 1 (f)
            float gc = __shfl(acc1[r], j, 64);        // gate 2 (cc)
            float go = __shfl(acc1[r], j + 8, 64);    // gate 3 (o)
            if (lane < 8) {
                float cn = sigmoidf_(gf) * cst[r] + sigmoidf_(gi) * fmaxf(gc, 0.f);
                float hn = sigmoidf_(go) * fmaxf(cn, 0.f);
                unsigned mk = (masks[r][s >> 5] >> (s & 31)) & 1u;
                if (mk) { cst[r] = cn; hst[r] = hn; }
            }
        }
        if (lane < 8) {
            unsigned long long outv = 0;
            #pragma unroll
            for (int r = 0; r < 4; ++r) {
                __hip_bfloat16 hb = __float2bfloat16(hst[r]);
                unsigned short bits;
                __builtin_memcpy(&bits, &hb, 2);
                bits |= (unsigned short)(((tag >> r) & 1u) << 15);  // h >= 0: sign free
                outv |= (unsigned long long)bits << (16 * r);
            }
            unsigned long long* dst =
                chbase + ((s + 1) & 1) * 512 + us * 32 + w * 8 + lane;
            __hip_atomic_store(dst, outv, __ATOMIC_RELAXED, __HIP_MEMORY_SCOPE_AGENT);
            if (s == T_ - 1) {
                #pragma unroll
                for (int r = 0; r < 4; ++r)
                    hfin[(size_t)(bg * 4 + r) * U_ + us * 32 + w * 8 + lane] =
                        __float2bfloat16(hst[r]);
            }
        }
    }
}

// ---------------------------------------------------------------------------
// FC layers
// ---------------------------------------------------------------------------
__global__ __launch_bounds__(256) void fc1_kernel(const __hip_bfloat16* __restrict__ h,
                                                  const float* __restrict__ W,
                                                  const float* __restrict__ bias,
                                                  float* __restrict__ y) {
    int b = blockIdx.x >> 2, ch = blockIdx.x & 3;
    __shared__ float xrow[U_];
    for (int i = threadIdx.x; i < U_; i += 256)
        xrow[i] = __bfloat162float(h[b * U_ + i]);
    __syncthreads();
    int n = ch * 256 + threadIdx.x;
    float acc = 0.f;
    #pragma unroll 4
    for (int k = 0; k < U_; ++k) acc = fmaf(xrow[k], W[(size_t)k * D1_ + n], acc);
    y[b * D1_ + n] = fmaxf(acc + bias[n], 0.f);
}

__global__ __launch_bounds__(256) void fc2_kernel(const float* __restrict__ x,
                                                  const float* __restrict__ W,
                                                  const float* __restrict__ bias,
                                                  float* __restrict__ y) {
    int b = blockIdx.x >> 2, ch = blockIdx.x & 3;
    __shared__ float xrow[D1_];
    for (int i = threadIdx.x; i < D1_; i += 256) xrow[i] = x[b * D1_ + i];
    __syncthreads();
    int n = ch * 256 + threadIdx.x;
    float acc = 0.f;
    #pragma unroll 4
    for (int k = 0; k < D1_; ++k) acc = fmaf(xrow[k], W[(size_t)k * D2_ + n], acc);
    y[b * D2_ + n] = fmaxf(acc + bias[n], 0.f);
}

// ---------------------------------------------------------------------------
// logits + softmax
// ---------------------------------------------------------------------------
__global__ __launch_bounds__(64) void out_kernel(const float* __restrict__ h2,
                                                 const float* __restrict__ Wo,
                                                 const float* __restrict__ bo,
                                                 float* __restrict__ out) {
    int b = blockIdx.x;
    __shared__ float xrow[D2_];
    __shared__ float lg[NC_];
    __shared__ float red[2];
    for (int i = threadIdx.x; i < D2_; i += 64) xrow[i] = h2[b * D2_ + i];
    __syncthreads();
    if (threadIdx.x < NC_) {
        float a = bo[threadIdx.x];
        for (int k = 0; k < D2_; ++k) a = fmaf(xrow[k], Wo[k * NC_ + threadIdx.x], a);
        lg[threadIdx.x] = a;
    }
    __syncthreads();
    if (threadIdx.x == 0) {
        float mx = lg[0];
        for (int c = 1; c < NC_; ++c) mx = fmaxf(mx, lg[c]);
        float sm = 0.f;
        for (int c = 0; c < NC_; ++c) sm += expf(lg[c] - mx);
        red[0] = mx; red[1] = 1.0f / sm;
    }
    __syncthreads();
    if (threadIdx.x < NC_)
        out[b * NC_ + threadIdx.x] = expf(lg[threadIdx.x] - red[0]) * red[1];
}

// ---------------------------------------------------------------------------
extern "C" void kernel_launch(void* const* d_in, const int* in_sizes, int n_in,
                              void* d_out, int out_size, void* d_ws, size_t ws_size,
                              hipStream_t stream) {
    const int*   tokens = (const int*)d_in[0];
    const float* emb    = (const float*)d_in[1];
    const float* Wx     = (const float*)d_in[2];
    const float* Wh     = (const float*)d_in[3];
    const float* b      = (const float*)d_in[4];
    const float* W1     = (const float*)d_in[5];
    const float* b1     = (const float*)d_in[6];
    const float* W2     = (const float*)d_in[7];
    const float* b2     = (const float*)d_in[8];
    const float* Wo     = (const float*)d_in[9];
    const float* bo     = (const float*)d_in[10];
    float* out = (float*)d_out;

    char* ws = (char*)d_ws;
    const size_t XG_BYTES  = (size_t)T_ * B_ * G4_ * 2;        // 134,217,728
    const size_t CH_BYTES  = (size_t)NBG_ * 2 * 512 * 8;       // 131,072
    const size_t HF_BYTES  = (size_t)B_ * U_ * 2;              // 65,536
    __hip_bfloat16* xg       = (__hip_bfloat16*)ws;
    unsigned long long* hch  = (unsigned long long*)(ws + XG_BYTES);
    __hip_bfloat16* hfin     = (__hip_bfloat16*)(ws + XG_BYTES + CH_BYTES);
    char* p = ws + XG_BYTES + CH_BYTES + HF_BYTES;
    float* h1            = (float*)p;                 p += (size_t)B_ * D1_ * 4;
    float* h2            = (float*)p;                 p += (size_t)B_ * D2_ * 4;
    __hip_bfloat16* xb   = (__hip_bfloat16*)p;        p += (size_t)B_ * T_ * KP_ * 2;
    __hip_bfloat16* wxT  = (__hip_bfloat16*)p;        // 2048*320*2 = 1.3 MB

    // no hch init needed: 0xAA poison reads as tag nibble 15, which can never
    // false-match before the buffer's first real write (tags cycle 1,3,..13
    // on each parity before 15 is expected)

    hipFuncSetAttribute((const void*)lstm_kernel,
                        hipFuncAttributeMaxDynamicSharedMemorySize, SMEM_TOTAL);

    prep_wxT<<<dim3(32, 5), 256, 0, stream>>>(Wx, wxT);
    prep_xb<<<(B_ * T_) / 4, 256, 0, stream>>>(tokens, emb, xb);
    xg_gemm<<<dim3(16, 256), 256, 0, stream>>>(xb, wxT, b, xg);
    lstm_kernel<<<256, 256, SMEM_TOTAL, stream>>>(xg, tokens, Wh, hch, hfin);
    fc1_kernel<<<256, 256, 0, stream>>>(hfin, W1, b1, h1);
    fc2_kernel<<<256, 256, 0, stream>>>(h1, W2, b2, h2);
    out_kernel<<<64, 64, 0, stream>>>(h2, Wo, bo, out);
}

// Round 8
// 1722.545 us; speedup vs baseline: 1.1897x; 1.1897x over previous
//
#include <hip/hip_runtime.h>
#include <hip/hip_bf16.h>

#define B_   64
#define T_   512
#define E_   300
#define U_   512
#define G4_  2048
#define D1_  1024
#define D2_  1024
#define NC_  20
#define KP_  320          // E_ padded to multiple of 32 for MFMA

// LSTM decomposition: 16 batch-groups (4 batches) x 16 unit-slices (32 units)
#define NBG_ 16
// dynamic LDS layout for lstm_kernel
#define WH_OFF   0
#define WH_BYTES (128 * 520 * 2)          // 133120: whsT[128][520] bf16
#define HS_OFF   (WH_OFF + WH_BYTES)
#define HS_BYTES (2 * 4 * 520 * 2)        // 8320: hs[parity][4 batches][520] bf16
#define MK_OFF   (HS_OFF + HS_BYTES)
#define MK_BYTES (4 * 16 * 4)             // 256:  masks[4][16]
#define SMEM_TOTAL (MK_OFF + MK_BYTES)    // 141696 <= 160 KiB

typedef __bf16 bf16x8 __attribute__((ext_vector_type(8)));
typedef float  f32x4  __attribute__((ext_vector_type(4)));

__device__ __forceinline__ float sigmoidf_(float x) { return 1.0f / (1.0f + __expf(-x)); }

__device__ __forceinline__ void gl_lds16(const void* g, void* l) {
    __builtin_amdgcn_global_load_lds(
        (const __attribute__((address_space(1))) unsigned int*)g,
        (__attribute__((address_space(3))) unsigned int*)l, 16, 0, 0);
}

__device__ __forceinline__ unsigned long long coh_load8(const unsigned long long* p) {
    uint2 v;
    asm volatile("global_load_dwordx2 %0, %1, off sc0 sc1\n\t"
                 "s_waitcnt vmcnt(0)"
                 : "=&v"(v) : "v"(p) : "memory");
    unsigned long long r;
    __builtin_memcpy(&r, &v, 8);
    return r;
}

__device__ __forceinline__ unsigned tag4_(unsigned long long v) {
    return (unsigned)(((v >> 15) & 1ull) | ((v >> 30) & 2ull) |
                      ((v >> 45) & 4ull) | ((v >> 60) & 8ull));
}

// ---------------------------------------------------------------------------
// prep: Wx (300x2048 f32) -> WxT[2048][320] bf16 (transposed, K zero-padded)
// ---------------------------------------------------------------------------
__global__ __launch_bounds__(256) void prep_wxT(const float* __restrict__ Wx,
                                                __hip_bfloat16* __restrict__ wxT) {
    __shared__ __hip_bfloat16 t[64][65];
    const int n0 = blockIdx.x * 64;   // 32 tiles
    const int k0 = blockIdx.y * 64;   // 5 tiles
    const int tid = threadIdx.x;
    for (int i = tid; i < 4096; i += 256) {
        int r = i >> 6, c = i & 63;
        int k = k0 + r;
        float v = (k < E_) ? Wx[(size_t)k * G4_ + n0 + c] : 0.f;
        t[r][c] = __float2bfloat16(v);
    }
    __syncthreads();
    for (int i = tid; i < 4096; i += 256) {
        int r = i >> 6, c = i & 63;
        wxT[(size_t)(n0 + r) * KP_ + k0 + c] = t[c][r];
    }
}

// ---------------------------------------------------------------------------
// prep: gather + cvt  xb[bt][k] = bf16(emb[tokens[bt]][k]), zero-padded K
// ---------------------------------------------------------------------------
__global__ __launch_bounds__(256) void prep_xb(const int* __restrict__ tokens,
                                               const float* __restrict__ emb,
                                               __hip_bfloat16* __restrict__ xb) {
    const int row = blockIdx.x * 4 + (threadIdx.x >> 6);
    const int ln  = threadIdx.x & 63;
    const int tok = tokens[row];
    const float* src = emb + (size_t)tok * E_;
    __hip_bfloat16* dst = xb + (size_t)row * KP_;
    for (int k = ln; k < KP_; k += 64)
        dst[k] = (k < E_) ? __float2bfloat16(src[k]) : __float2bfloat16(0.f);
}

// ---------------------------------------------------------------------------
// xg GEMM (MFMA): xg[t][b][n] = xb[bt] @ WxT^T + bias   (m97-style 128x128)
// ---------------------------------------------------------------------------
__global__ __launch_bounds__(256) void xg_gemm(const __hip_bfloat16* __restrict__ xb,
                                               const __hip_bfloat16* __restrict__ wxT,
                                               const float* __restrict__ bias,
                                               __hip_bfloat16* __restrict__ xg) {
    const int n0g = blockIdx.x * 128;   // 16
    const int bt0 = blockIdx.y * 128;   // 256
    const int tid = threadIdx.x;
    const int w   = tid >> 6;
    const int ln  = tid & 63;
    const int fn  = ln & 15;
    const int quad = ln >> 4;
    const int m0  = (w >> 1) * 64;
    const int n0w = (w & 1) * 64;

    __shared__ __align__(16) __hip_bfloat16 As[128 * 32];
    __shared__ __align__(16) __hip_bfloat16 Bs[128 * 32];

    f32x4 acc[4][4];
    #pragma unroll
    for (int im = 0; im < 4; ++im)
        #pragma unroll
        for (int in = 0; in < 4; ++in)
            acc[im][in] = (f32x4){0.f, 0.f, 0.f, 0.f};

    const __hip_bfloat16* ga = xb  + (size_t)(bt0 + w * 32 + (ln >> 2)) * KP_ + (ln & 3) * 8;
    const __hip_bfloat16* gb = wxT + (size_t)(n0g + w * 32 + (ln >> 2)) * KP_ + (ln & 3) * 8;

    for (int kt = 0; kt < KP_ / 32; ++kt) {
        gl_lds16(ga,             &As[(w * 32) * 32]);
        gl_lds16(ga + 16 * KP_,  &As[(w * 32 + 16) * 32]);
        gl_lds16(gb,             &Bs[(w * 32) * 32]);
        gl_lds16(gb + 16 * KP_,  &Bs[(w * 32 + 16) * 32]);
        ga += 32; gb += 32;
        __syncthreads();

        bf16x8 af[4], bfr[4];
        #pragma unroll
        for (int im = 0; im < 4; ++im)
            af[im] = *(const bf16x8*)&As[(m0 + im * 16 + fn) * 32 + quad * 8];
        #pragma unroll
        for (int in = 0; in < 4; ++in)
            bfr[in] = *(const bf16x8*)&Bs[(n0w + in * 16 + fn) * 32 + quad * 8];
        #pragma unroll
        for (int im = 0; im < 4; ++im)
            #pragma unroll
            for (int in = 0; in < 4; ++in)
                acc[im][in] = __builtin_amdgcn_mfma_f32_16x16x32_bf16(
                    af[im], bfr[in], acc[im][in], 0, 0, 0);
        __syncthreads();
    }

    #pragma unroll
    for (int in = 0; in < 4; ++in) {
        const int n = n0g + n0w + in * 16 + fn;
        const float bv = bias[n];
        #pragma unroll
        for (int im = 0; im < 4; ++im) {
            #pragma unroll
            for (int r = 0; r < 4; ++r) {
                int m = bt0 + m0 + im * 16 + quad * 4 + r;   // bt = b*T + t
                int bb = m >> 9, tt = m & 511;
                xg[(size_t)(tt * B_ + bb) * G4_ + n] =
                    __float2bfloat16(acc[im][in][r] + bv);
            }
        }
    }
}

// ---------------------------------------------------------------------------
// LSTM: 256 blocks = 16 bgroups (4 batches) x 16 uslices (32 units).
// Exchange: per-unit 8B chunks {4x bf16 h (>=0), 4-bit step tag in the sign
// bits} fire-and-forget through coherent stores; consumers poll the payload
// with per-chunk selective retry (R6 control flow). Gate-in-wave mapping:
// a wave computes all 4 gates for its 8 units, so gates are harvested with
// intra-wave shuffles — no gbuf, ONE __syncthreads per step. 1 block/CU.
// ---------------------------------------------------------------------------
__global__ __launch_bounds__(256, 1) void lstm_kernel(const __hip_bfloat16* __restrict__ xg,
                                                      const int* __restrict__ tokens,
                                                      const float* __restrict__ Wh,
                                                      unsigned long long* __restrict__ hch,
                                                      __hip_bfloat16* __restrict__ hfin) {
    extern __shared__ char smem[];
    __hip_bfloat16 (*whsT)[520] = (__hip_bfloat16(*)[520])(smem + WH_OFF);  // [lc][k]
    unsigned short* hsb         = (unsigned short*)(smem + HS_OFF); // [p][b][520]
    unsigned (*masks)[16]       = (unsigned(*)[16])(smem + MK_OFF);

    const int tid  = threadIdx.x;
    const int w    = tid >> 6;
    const int lane = tid & 63;
    const int fn   = lane & 15;
    const int quad = lane >> 4;
    const int us   = blockIdx.x & 15;   // unit-slice: units [us*32, us*32+32)
    const int bg   = blockIdx.x >> 4;   // batch-group: batches [bg*4, bg*4+4)

    // stage Wh slice with wave-local gate mapping:
    // lc = ww*32 + half*16 + f ; gate g = half*2 + (f>>3); unit u = ww*8 + (f&7)
    for (int idx = tid; idx < 128 * 512; idx += 256) {
        int lc = idx & 127, k = idx >> 7;
        int ww = lc >> 5, r = lc & 31;
        int half = r >> 4, f = r & 15;
        int g = half * 2 + (f >> 3);
        int u = ww * 8 + (f & 7);
        int gcol = g * 512 + us * 32 + u;
        whsT[lc][k] = __float2bfloat16(Wh[(size_t)k * G4_ + gcol]);
    }
    // token!=0 bitmasks for the 4 batches
    if (tid < 64) {
        int b = tid >> 4, wi = tid & 15;
        const int4* tp = (const int4*)(tokens + (size_t)(bg * 4 + b) * T_ + wi * 32);
        unsigned bits = 0;
        #pragma unroll
        for (int q = 0; q < 8; ++q) {
            int4 v = tp[q];
            bits |= (v.x != 0 ? 1u : 0u) << (q * 4 + 0);
            bits |= (v.y != 0 ? 1u : 0u) << (q * 4 + 1);
            bits |= (v.z != 0 ? 1u : 0u) << (q * 4 + 2);
            bits |= (v.w != 0 ? 1u : 0u) << (q * 4 + 3);
        }
        masks[b][wi] = bits;
    }
    // hs zero (h_0 = 0, both parities)
    for (int i = tid; i < 2 * 4 * 520; i += 256) hsb[i] = 0;
    __syncthreads();

    // weight fragments (compiler may keep in regs or re-read LDS; whsT stays)
    const int lc0 = w * 32 + fn;
    bf16x8 wfr0[16], wfr1[16];
    #pragma unroll
    for (int kk = 0; kk < 16; ++kk) {
        wfr0[kk] = *(const bf16x8*)&whsT[lc0][kk * 32 + quad * 8];       // gates 0,1
        wfr1[kk] = *(const bf16x8*)&whsT[lc0 + 16][kk * 32 + quad * 8];  // gates 2,3
    }

    // per-lane state (lanes 0..7 of each wave): unit w*8+lane, batches 0..3
    float cst[4] = {0.f, 0.f, 0.f, 0.f};
    float hst[4] = {0.f, 0.f, 0.f, 0.f};

    // stager mapping: thread t stages units t and t+256
    unsigned long long* chbase = hch + (size_t)bg * 2 * 512;   // [parity][unit]
    const unsigned long long* cp0 = chbase + tid;              // + parity*512
    const unsigned long long* cp1 = chbase + tid + 256;

    // xg column offsets for quad-0 lanes (gate g, unit w*8+(fn&7))
    const int xc0 = (fn >> 3) * 512 + us * 32 + w * 8 + (fn & 7);          // gates 0/1
    const int xc1 = xc0 + 1024;                                            // gates 2/3

    for (int s = 0; s < T_; ++s) {
        const int p = s & 1;
        unsigned short* hsu = hsb + p * (4 * 520);

        // xg prefetch (normal loads; in flight during the stage polls)
        float xv0[4], xv1[4];
        if (quad == 0) {
            const __hip_bfloat16* xp = xg + (size_t)(s * B_ + bg * 4) * G4_;
            #pragma unroll
            for (int r = 0; r < 4; ++r) {
                xv0[r] = __bfloat162float(xp[(size_t)r * G4_ + xc0]);
                xv1[r] = __bfloat162float(xp[(size_t)r * G4_ + xc1]);
            }
        }

        // stage h_s: poll own 2 chunks (tag nibble = s&15), scatter to LDS
        if (s > 0) {
            const unsigned exp4 = (unsigned)s & 0xFu;
            const unsigned long long* a0 = cp0 + p * 512;
            const unsigned long long* a1 = cp1 + p * 512;
            unsigned long long v0, v1;
            {
                uint2 t0, t1;
                asm volatile(
                    "global_load_dwordx2 %0, %2, off sc0 sc1\n\t"
                    "global_load_dwordx2 %1, %3, off sc0 sc1\n\t"
                    "s_waitcnt vmcnt(0)"
                    : "=&v"(t0), "=&v"(t1) : "v"(a0), "v"(a1) : "memory");
                __builtin_memcpy(&v0, &t0, 8);
                __builtin_memcpy(&v1, &t1, 8);
            }
            while (tag4_(v0) != exp4) {
                __builtin_amdgcn_s_sleep(1);
                v0 = coh_load8(a0);
            }
            {
                unsigned long long pl = v0 & 0x7FFF7FFF7FFF7FFFull;
                hsu[0 * 520 + tid] = (unsigned short)(pl);
                hsu[1 * 520 + tid] = (unsigned short)(pl >> 16);
                hsu[2 * 520 + tid] = (unsigned short)(pl >> 32);
                hsu[3 * 520 + tid] = (unsigned short)(pl >> 48);
            }
            while (tag4_(v1) != exp4) {
                __builtin_amdgcn_s_sleep(1);
                v1 = coh_load8(a1);
            }
            {
                unsigned long long pl = v1 & 0x7FFF7FFF7FFF7FFFull;
                hsu[0 * 520 + tid + 256] = (unsigned short)(pl);
                hsu[1 * 520 + tid + 256] = (unsigned short)(pl >> 16);
                hsu[2 * 520 + tid + 256] = (unsigned short)(pl >> 32);
                hsu[3 * 520 + tid + 256] = (unsigned short)(pl >> 48);
            }
        }
        __syncthreads();   // the ONE barrier: h_s staged -> GEMM may read

        // GEMM over 16 K-slices (poll-free)
        f32x4 acc0 = (f32x4){0.f, 0.f, 0.f, 0.f};
        f32x4 acc1 = (f32x4){0.f, 0.f, 0.f, 0.f};
        if (quad == 0) {
            #pragma unroll
            for (int r = 0; r < 4; ++r) { acc0[r] = xv0[r]; acc1[r] = xv1[r]; }
        }
        #pragma unroll
        for (int ks = 0; ks < 16; ++ks) {
            bf16x8 afr = *(const bf16x8*)&hsu[(fn & 3) * 520 + ks * 32 + quad * 8];
            acc0 = __builtin_amdgcn_mfma_f32_16x16x32_bf16(afr, wfr0[ks], acc0, 0, 0, 0);
            acc1 = __builtin_amdgcn_mfma_f32_16x16x32_bf16(afr, wfr1[ks], acc1, 0, 0, 0);
        }

        // harvest gates via intra-wave shuffles; lanes 0..7 update + store
        const int j = lane & 7;
        const unsigned tag = (unsigned)(s + 1) & 0xFu;
        #pragma unroll
        for (int r = 0; r < 4; ++r) {
            float gi = __shfl(acc0[r], j, 64);        // gate 0 (i),  unit w*8+j
            float gf = __shfl(acc0[r], j + 8, 64);    // gate 1 (f)
            float gc = __shfl(acc1[r], j, 64);        // gate 2 (cc)
            float go = __shfl(acc1[r], j + 8, 64);    // gate 3 (o)
            if (lane < 8) {
                float cn = sigmoidf_(gf) * cst[r] + sigmoidf_(gi) * fmaxf(gc, 0.f);
                float hn = sigmoidf_(go) * fmaxf(cn, 0.f);
                unsigned mk = (masks[r][s >> 5] >> (s & 31)) & 1u;
                if (mk) { cst[r] = cn; hst[r] = hn; }
            }
        }
        if (lane < 8) {
            unsigned long long outv = 0;
            #pragma unroll
            for (int r = 0; r < 4; ++r) {
                __hip_bfloat16 hb = __float2bfloat16(hst[r]);
                unsigned short bits;
                __builtin_memcpy(&bits, &hb, 2);
                bits |= (unsigned short)(((tag >> r) & 1u) << 15);  // h >= 0: sign free
                outv |= (unsigned long long)bits << (16 * r);
            }
            unsigned long long* dst =
                chbase + ((s + 1) & 1) * 512 + us * 32 + w * 8 + lane;
            __hip_atomic_store(dst, outv, __ATOMIC_RELAXED, __HIP_MEMORY_SCOPE_AGENT);
            if (s == T_ - 1) {
                #pragma unroll
                for (int r = 0; r < 4; ++r)
                    hfin[(size_t)(bg * 4 + r) * U_ + us * 32 + w * 8 + lane] =
                        __float2bfloat16(hst[r]);
            }
        }
        // no second barrier: arriving at the next step's barrier implies all
        // threads finished this step's MFMA reads of hsu (program order), so
        // parity-buffer reuse two steps later can never race a reader.
    }
}

// ---------------------------------------------------------------------------
// FC layers
// ---------------------------------------------------------------------------
__global__ __launch_bounds__(256) void fc1_kernel(const __hip_bfloat16* __restrict__ h,
                                                  const float* __restrict__ W,
                                                  const float* __restrict__ bias,
                                                  float* __restrict__ y) {
    int b = blockIdx.x >> 2, ch = blockIdx.x & 3;
    __shared__ float xrow[U_];
    for (int i = threadIdx.x; i < U_; i += 256)
        xrow[i] = __bfloat162float(h[b * U_ + i]);
    __syncthreads();
    int n = ch * 256 + threadIdx.x;
    float acc = 0.f;
    #pragma unroll 4
    for (int k = 0; k < U_; ++k) acc = fmaf(xrow[k], W[(size_t)k * D1_ + n], acc);
    y[b * D1_ + n] = fmaxf(acc + bias[n], 0.f);
}

__global__ __launch_bounds__(256) void fc2_kernel(const float* __restrict__ x,
                                                  const float* __restrict__ W,
                                                  const float* __restrict__ bias,
                                                  float* __restrict__ y) {
    int b = blockIdx.x >> 2, ch = blockIdx.x & 3;
    __shared__ float xrow[D1_];
    for (int i = threadIdx.x; i < D1_; i += 256) xrow[i] = x[b * D1_ + i];
    __syncthreads();
    int n = ch * 256 + threadIdx.x;
    float acc = 0.f;
    #pragma unroll 4
    for (int k = 0; k < D1_; ++k) acc = fmaf(xrow[k], W[(size_t)k * D2_ + n], acc);
    y[b * D2_ + n] = fmaxf(acc + bias[n], 0.f);
}

// ---------------------------------------------------------------------------
// logits + softmax
// ---------------------------------------------------------------------------
__global__ __launch_bounds__(64) void out_kernel(const float* __restrict__ h2,
                                                 const float* __restrict__ Wo,
                                                 const float* __restrict__ bo,
                                                 float* __restrict__ out) {
    int b = blockIdx.x;
    __shared__ float xrow[D2_];
    __shared__ float lg[NC_];
    __shared__ float red[2];
    for (int i = threadIdx.x; i < D2_; i += 64) xrow[i] = h2[b * D2_ + i];
    __syncthreads();
    if (threadIdx.x < NC_) {
        float a = bo[threadIdx.x];
        for (int k = 0; k < D2_; ++k) a = fmaf(xrow[k], Wo[k * NC_ + threadIdx.x], a);
        lg[threadIdx.x] = a;
    }
    __syncthreads();
    if (threadIdx.x == 0) {
        float mx = lg[0];
        for (int c = 1; c < NC_; ++c) mx = fmaxf(mx, lg[c]);
        float sm = 0.f;
        for (int c = 0; c < NC_; ++c) sm += expf(lg[c] - mx);
        red[0] = mx; red[1] = 1.0f / sm;
    }
    __syncthreads();
    if (threadIdx.x < NC_)
        out[b * NC_ + threadIdx.x] = expf(lg[threadIdx.x] - red[0]) * red[1];
}

// ---------------------------------------------------------------------------
extern "C" void kernel_launch(void* const* d_in, const int* in_sizes, int n_in,
                              void* d_out, int out_size, void* d_ws, size_t ws_size,
                              hipStream_t stream) {
    const int*   tokens = (const int*)d_in[0];
    const float* emb    = (const float*)d_in[1];
    const float* Wx     = (const float*)d_in[2];
    const float* Wh     = (const float*)d_in[3];
    const float* b      = (const float*)d_in[4];
    const float* W1     = (const float*)d_in[5];
    const float* b1     = (const float*)d_in[6];
    const float* W2     = (const float*)d_in[7];
    const float* b2     = (const float*)d_in[8];
    const float* Wo     = (const float*)d_in[9];
    const float* bo     = (const float*)d_in[10];
    float* out = (float*)d_out;

    char* ws = (char*)d_ws;
    const size_t XG_BYTES  = (size_t)T_ * B_ * G4_ * 2;        // 134,217,728
    const size_t CH_BYTES  = (size_t)NBG_ * 2 * 512 * 8;       // 131,072
    const size_t HF_BYTES  = (size_t)B_ * U_ * 2;              // 65,536
    __hip_bfloat16* xg       = (__hip_bfloat16*)ws;
    unsigned long long* hch  = (unsigned long long*)(ws + XG_BYTES);
    __hip_bfloat16* hfin     = (__hip_bfloat16*)(ws + XG_BYTES + CH_BYTES);
    char* p = ws + XG_BYTES + CH_BYTES + HF_BYTES;
    float* h1            = (float*)p;                 p += (size_t)B_ * D1_ * 4;
    float* h2            = (float*)p;                 p += (size_t)B_ * D2_ * 4;
    __hip_bfloat16* xb   = (__hip_bfloat16*)p;        p += (size_t)B_ * T_ * KP_ * 2;
    __hip_bfloat16* wxT  = (__hip_bfloat16*)p;        // 2048*320*2 = 1.3 MB

    // no hch init needed: 0xAA poison reads as tag nibble 15; parity-1's
    // first expected tag is 1 and parity-0's is 2, and inductive skew <= 1
    // step keeps every cell one write ahead of its reader thereafter.

    hipFuncSetAttribute((const void*)lstm_kernel,
                        hipFuncAttributeMaxDynamicSharedMemorySize, SMEM_TOTAL);

    prep_wxT<<<dim3(32, 5), 256, 0, stream>>>(Wx, wxT);
    prep_xb<<<(B_ * T_) / 4, 256, 0, stream>>>(tokens, emb, xb);
    xg_gemm<<<dim3(16, 256), 256, 0, stream>>>(xb, wxT, b, xg);
    lstm_kernel<<<256, 256, SMEM_TOTAL, stream>>>(xg, tokens, Wh, hch, hfin);
    fc1_kernel<<<256, 256, 0, stream>>>(hfin, W1, b1, h1);
    fc2_kernel<<<256, 256, 0, stream>>>(h1, W2, b2, h2);
    out_kernel<<<64, 64, 0, stream>>>(h2, Wo, bo, out);
}